// Round 3
// baseline (591.818 us; speedup 1.0000x reference)
//
#include <hip/hip_runtime.h>

// ---------------------------------------------------------------------------
// Shifted-window attention (Swin), MI355X bf16-MFMA, round 6.
// Identical structure to round 5, ONE change: register budget pinned via
// amdgpu_waves_per_eu(2,2) (+flat_work_group_size) so the backend allocates
// up to 256 VGPRs for the 2-blocks/CU occupancy the 80KiB LDS permits,
// instead of spilling ~70MB of scratch to hit a useless 128-VGPR budget.
// ---------------------------------------------------------------------------

typedef __bf16 bf16;
typedef __bf16 bf16x8 __attribute__((ext_vector_type(8)));
typedef __bf16 bf16x4 __attribute__((ext_vector_type(4)));
typedef float f32x4 __attribute__((ext_vector_type(4)));

#define QKV_SCALE 0.17677669529663687f

// workspace offsets (bytes); total 7,471,104
#define BM_OFF 0u            // bias+mask bf16, fragment order [768][4096]
#define WQ_OFF 6291456u      // wqkv bf16 [1152][384]
#define WP_OFF 7176192u      // wproj bf16 [384][384]

// --------------------------------------------------------------------------
// prep: [0,288) weight cvt   [288,12576) bias+mask table
// --------------------------------------------------------------------------
__global__ __launch_bounds__(256) void k_prep(
    const float* __restrict__ wqkv, const float* __restrict__ wproj,
    const float* __restrict__ table, bf16* __restrict__ wq,
    bf16* __restrict__ wp, bf16* __restrict__ bm) {
  int blk = blockIdx.x;
  if (blk < 288) {
    int idx = blk * 256 + threadIdx.x;            // < 73728
    const float* src; bf16* dst; int off;
    if (idx < 55296) { src = wqkv; dst = wq; off = idx * 8; }
    else             { src = wproj; dst = wp; off = (idx - 55296) * 8; }
    float4 a0 = *(const float4*)(src + off);
    float4 a1 = *(const float4*)(src + off + 4);
    bf16x8 o;
    o[0] = (bf16)a0.x; o[1] = (bf16)a0.y; o[2] = (bf16)a0.z; o[3] = (bf16)a0.w;
    o[4] = (bf16)a1.x; o[5] = (bf16)a1.y; o[6] = (bf16)a1.z; o[7] = (bf16)a1.w;
    *(bf16x8*)(dst + off) = o;
  } else {
    // frag-ordered bias+mask: bm[(wi*12+h)*4096 + (ts*4+c)*256 + lane*4 + r]
    int idx = (blk - 288) * 256 + threadIdx.x;    // < 3,145,728
    int r = idx & 3;
    int lane = (idx >> 2) & 63;
    int c = (idx >> 8) & 3;
    int ts = (idx >> 10) & 3;
    int comb = idx >> 12;                          // < 768
    int h = comb % 12, wi = comb / 12;
    int i = ts * 16 + ((lane >> 4) << 2) + r;
    int j = c * 16 + (lane & 15);
    float v;
    if (j >= 49) v = -30000.f;
    else if (i >= 49) v = 0.f;
    else {
      int wy = wi >> 3, wx = wi & 7;
      int iy = i / 7, ix = i - iy * 7;
      int jy = j / 7, jx = j - jy * 7;
      int rel = (iy - jy + 6) * 13 + (ix - jx + 6);
      int gyi = wy * 7 + iy, gxi = wx * 7 + ix;
      int gyj = wy * 7 + jy, gxj = wx * 7 + jx;
      int ri = ((gyi < 49) ? 0 : ((gyi < 53) ? 1 : 2)) * 3 +
               ((gxi < 49) ? 0 : ((gxi < 53) ? 1 : 2));
      int rj = ((gyj < 49) ? 0 : ((gyj < 53) ? 1 : 2)) * 3 +
               ((gxj < 49) ? 0 : ((gxj < 53) ? 1 : 2));
      v = table[rel * 12 + h] + ((ri == rj) ? 0.f : -100.f);
    }
    bm[idx] = (bf16)v;
  }
}

// --------------------------------------------------------------------------
// Fused per-window kernel: 4 waves, 3 heads/wave, 2 blocks/CU.
// LDS: XAB 48K (X tile, later attn-output tile) + S 4x8K stage = 81920 B.
// Register budget pinned to the real occupancy: 2 waves/EU -> <=256 VGPR.
// --------------------------------------------------------------------------
__global__
__attribute__((amdgpu_flat_work_group_size(256, 256), amdgpu_waves_per_eu(2, 2)))
void k_fused(
    const float* __restrict__ x, const bf16* __restrict__ wq,
    const float* __restrict__ bqkv, const bf16* __restrict__ bm,
    const bf16* __restrict__ wp, const float* __restrict__ bp,
    float* __restrict__ out) {
  __shared__ __align__(16) bf16 XAB[64 * 384];   // X tile, then AB overlay
  __shared__ __align__(16) bf16 S[4][4096];      // per-wave Q/K then V; P overlay

  int tid = threadIdx.x;
  int wv = tid >> 6, lane = tid & 63, l16 = lane & 15, q4 = lane >> 4;
  int w = blockIdx.x;
  int wi = w & 63;
  int b = w >> 6;
  int wy = wi >> 3, wx = wi & 7;

  // ---- stage X: gather (roll -3,-3) + fp32->bf16 + swizzled ds_write
#pragma unroll
  for (int it = 0; it < 12; ++it) {
    int c = it * 256 + tid;            // 16B-chunk id, < 3072
    int row = c / 48, gcol = c - row * 48;
    bf16x8 o;
    if (row < 49) {
      int ty = row / 7, tx = row - ty * 7;
      int sy = wy * 7 + ty + 3; if (sy >= 56) sy -= 56;
      int sx = wx * 7 + tx + 3; if (sx >= 56) sx -= 56;
      const float* src = x + (size_t)((b * 56 + sy) * 56 + sx) * 384 + gcol * 8;
      float4 a0 = *(const float4*)src;
      float4 a1 = *(const float4*)(src + 4);
      o[0] = (bf16)a0.x; o[1] = (bf16)a0.y; o[2] = (bf16)a0.z; o[3] = (bf16)a0.w;
      o[4] = (bf16)a1.x; o[5] = (bf16)a1.y; o[6] = (bf16)a1.z; o[7] = (bf16)a1.w;
    } else {
#pragma unroll
      for (int j = 0; j < 8; ++j) o[j] = (bf16)0.f;
    }
    *(bf16x8*)(XAB + row * 384 + ((gcol ^ (row & 7)) << 3)) = o;
  }
  __syncthreads();

  const f32x4 zero4 = {0.f, 0.f, 0.f, 0.f};
  bf16x8 op[3][4];                     // packed attn output, 3 heads x 4 strips

#pragma unroll
  for (int hr = 0; hr < 3; ++hr) {
    asm volatile("" ::: "memory");     // no cross-head CSE of LDS reads
    int h = wv * 3 + hr;

    // ---- QKV GEMM: M=64, N=96 (q0 q1 k0 k1 v0 v1), K=384
    f32x4 acc[4][6];
#pragma unroll
    for (int a = 0; a < 4; ++a)
#pragma unroll
      for (int bb = 0; bb < 6; ++bb) acc[a][bb] = zero4;

    const bf16* wrow[6];
#pragma unroll
    for (int ci = 0; ci < 6; ++ci) {
      int part = ci >> 1, cc = ci & 1;
      wrow[ci] = wq + (size_t)(part * 384 + h * 32 + cc * 16 + l16) * 384 + q4 * 8;
    }
#pragma unroll
    for (int ks = 0; ks < 12; ++ks) {
      bf16x8 af[4], bfr[6];
#pragma unroll
      for (int mi = 0; mi < 4; ++mi) {
        int m = mi * 16 + l16;
        int g = ks * 4 + q4;
        af[mi] = *(const bf16x8*)(XAB + m * 384 + ((g ^ (m & 7)) << 3));
      }
#pragma unroll
      for (int ci = 0; ci < 6; ++ci)
        bfr[ci] = *(const bf16x8*)(wrow[ci] + ks * 32);
      __builtin_amdgcn_s_setprio(1);
#pragma unroll
      for (int mi = 0; mi < 4; ++mi)
#pragma unroll
        for (int ci = 0; ci < 6; ++ci)
          acc[mi][ci] = __builtin_amdgcn_mfma_f32_16x16x32_bf16(
              af[mi], bfr[ci], acc[mi][ci], 0, 0, 0);
      __builtin_amdgcn_s_setprio(0);
    }

    // ---- epilogue pass 1: Q (scaled) + K -> S[wv][0..4095]
#pragma unroll
    for (int ci = 0; ci < 4; ++ci) {
      int part = ci >> 1, cc = ci & 1;
      float bias = bqkv[part * 384 + h * 32 + cc * 16 + l16];
      float scl = (part == 0) ? QKV_SCALE : 1.0f;
      bf16* dst = &S[wv][part * 2048 + cc * 16 + l16];
#pragma unroll
      for (int mi = 0; mi < 4; ++mi)
#pragma unroll
        for (int r = 0; r < 4; ++r)
          dst[(mi * 16 + q4 * 4 + r) * 32] = (bf16)((acc[mi][ci][r] + bias) * scl);
    }
    __builtin_amdgcn_wave_barrier();

    bf16x8 qf[4], kf[4];
#pragma unroll
    for (int c = 0; c < 4; ++c) {
      qf[c] = *(const bf16x8*)(&S[wv][0] + (c * 16 + l16) * 32 + q4 * 8);
      kf[c] = *(const bf16x8*)(&S[wv][2048] + (c * 16 + l16) * 32 + q4 * 8);
    }
    __builtin_amdgcn_wave_barrier();

    // ---- epilogue pass 2: V overwrites Q region S[wv][0..2047]
#pragma unroll
    for (int ci = 4; ci < 6; ++ci) {
      int cc = ci & 1;
      float bias = bqkv[2 * 384 + h * 32 + cc * 16 + l16];
      bf16* dst = &S[wv][cc * 16 + l16];
#pragma unroll
      for (int mi = 0; mi < 4; ++mi)
#pragma unroll
        for (int r = 0; r < 4; ++r)
          dst[(mi * 16 + q4 * 4 + r) * 32] = (bf16)(acc[mi][ci][r] + bias);
    }
    __builtin_amdgcn_wave_barrier();

    bf16x8 vf[2][2];
#pragma unroll
    for (int half = 0; half < 2; ++half)
#pragma unroll
      for (int c2 = 0; c2 < 2; ++c2)
#pragma unroll
        for (int j = 0; j < 8; ++j)
          vf[half][c2][j] = S[wv][(half * 32 + q4 * 8 + j) * 32 + c2 * 16 + l16];
    __builtin_amdgcn_wave_barrier();   // vf read < P overlay writes

    // ---- attention (P overlays dead V region of S[wv], layout [16][72])
    const bf16* bmh = bm + ((size_t)(wi * 12 + h) << 12);
#pragma unroll
    for (int ts = 0; ts < 4; ++ts) {
      f32x4 s[4];
#pragma unroll
      for (int c = 0; c < 4; ++c)
        s[c] = __builtin_amdgcn_mfma_f32_16x16x32_bf16(qf[ts], kf[c], zero4, 0, 0, 0);
#pragma unroll
      for (int c = 0; c < 4; ++c) {
        bf16x4 bv = *(const bf16x4*)(bmh + (ts * 4 + c) * 256 + lane * 4);
#pragma unroll
        for (int r = 0; r < 4; ++r) s[c][r] += (float)bv[r];
      }
#pragma unroll
      for (int r = 0; r < 4; ++r) {
        float m = fmaxf(fmaxf(s[0][r], s[1][r]), fmaxf(s[2][r], s[3][r]));
        m = fmaxf(m, __shfl_xor(m, 1));
        m = fmaxf(m, __shfl_xor(m, 2));
        m = fmaxf(m, __shfl_xor(m, 4));
        m = fmaxf(m, __shfl_xor(m, 8));
        float e0 = __expf(s[0][r] - m);
        float e1 = __expf(s[1][r] - m);
        float e2 = __expf(s[2][r] - m);
        float e3 = __expf(s[3][r] - m);
        float sm = e0 + e1 + e2 + e3;
        sm += __shfl_xor(sm, 1);
        sm += __shfl_xor(sm, 2);
        sm += __shfl_xor(sm, 4);
        sm += __shfl_xor(sm, 8);
        float inv = 1.0f / sm;
        int ir = q4 * 4 + r;
        S[wv][ir * 72 + l16] = (bf16)(e0 * inv);
        S[wv][ir * 72 + 16 + l16] = (bf16)(e1 * inv);
        S[wv][ir * 72 + 32 + l16] = (bf16)(e2 * inv);
        S[wv][ir * 72 + 48 + l16] = (bf16)(e3 * inv);
      }
      __builtin_amdgcn_wave_barrier();   // pin ds_write < ds_read order
      bf16x8 p0 = *(const bf16x8*)&S[wv][l16 * 72 + q4 * 8];
      bf16x8 p1 = *(const bf16x8*)&S[wv][l16 * 72 + 32 + q4 * 8];
      f32x4 o0 = __builtin_amdgcn_mfma_f32_16x16x32_bf16(p0, vf[0][0], zero4, 0, 0, 0);
      o0 = __builtin_amdgcn_mfma_f32_16x16x32_bf16(p1, vf[1][0], o0, 0, 0, 0);
      f32x4 o1 = __builtin_amdgcn_mfma_f32_16x16x32_bf16(p0, vf[0][1], zero4, 0, 0, 0);
      o1 = __builtin_amdgcn_mfma_f32_16x16x32_bf16(p1, vf[1][1], o1, 0, 0, 0);
      __builtin_amdgcn_wave_barrier();   // pin ds_read < next strip's ds_write
      bf16x8 o8;
      o8[0] = (bf16)o0[0]; o8[1] = (bf16)o0[1];
      o8[2] = (bf16)o0[2]; o8[3] = (bf16)o0[3];
      o8[4] = (bf16)o1[0]; o8[5] = (bf16)o1[1];
      o8[6] = (bf16)o1[2]; o8[7] = (bf16)o1[3];
      op[hr][ts] = o8;
    }
  }

  // ---- all X reads done; flush attn output over X with the same swizzle
  __syncthreads();
#pragma unroll
  for (int hr = 0; hr < 3; ++hr) {
    int h = wv * 3 + hr;
#pragma unroll
    for (int ts = 0; ts < 4; ++ts) {
#pragma unroll
      for (int r = 0; r < 4; ++r) {
        int i = ts * 16 + q4 * 4 + r;
        int isw = i & 7;
        int c0 = h * 32 + l16;
        XAB[i * 384 + (((c0 >> 3) ^ isw) << 3) + (c0 & 7)] = op[hr][ts][r];
        int c1 = c0 + 16;
        XAB[i * 384 + (((c1 >> 3) ^ isw) << 3) + (c1 & 7)] = op[hr][ts][4 + r];
      }
    }
  }
  __syncthreads();

  // ---- proj GEMM: M=64, N=96/wave, K=384, A from XAB (same swizzle)
  {
    f32x4 pacc[4][6];
#pragma unroll
    for (int a = 0; a < 4; ++a)
#pragma unroll
      for (int bb = 0; bb < 6; ++bb) pacc[a][bb] = zero4;

    const bf16* wrow[6];
#pragma unroll
    for (int ci = 0; ci < 6; ++ci)
      wrow[ci] = wp + (size_t)(wv * 96 + ci * 16 + l16) * 384 + q4 * 8;
#pragma unroll
    for (int ks = 0; ks < 12; ++ks) {
      bf16x8 af[4], bfr[6];
#pragma unroll
      for (int mi = 0; mi < 4; ++mi) {
        int m = mi * 16 + l16;
        int g = ks * 4 + q4;
        af[mi] = *(const bf16x8*)(XAB + m * 384 + ((g ^ (m & 7)) << 3));
      }
#pragma unroll
      for (int ci = 0; ci < 6; ++ci)
        bfr[ci] = *(const bf16x8*)(wrow[ci] + ks * 32);
      __builtin_amdgcn_s_setprio(1);
#pragma unroll
      for (int mi = 0; mi < 4; ++mi)
#pragma unroll
        for (int ci = 0; ci < 6; ++ci)
          pacc[mi][ci] = __builtin_amdgcn_mfma_f32_16x16x32_bf16(
              af[mi], bfr[ci], pacc[mi][ci], 0, 0, 0);
      __builtin_amdgcn_s_setprio(0);
    }

    // epilogue: +bias, scatter with roll(+3,+3)
    float bias6[6]; int col6[6];
#pragma unroll
    for (int ci = 0; ci < 6; ++ci) {
      col6[ci] = wv * 96 + ci * 16 + l16;
      bias6[ci] = bp[col6[ci]];
    }
#pragma unroll
    for (int mi = 0; mi < 4; ++mi) {
#pragma unroll
      for (int r = 0; r < 4; ++r) {
        int t = mi * 16 + q4 * 4 + r;
        if (t < 49) {
          int ty = t / 7, tx = t - ty * 7;
          int gy = wy * 7 + ty + 3; if (gy >= 56) gy -= 56;
          int gx = wx * 7 + tx + 3; if (gx >= 56) gx -= 56;
          float* orow = out + (size_t)((b * 56 + gy) * 56 + gx) * 384;
#pragma unroll
          for (int ci = 0; ci < 6; ++ci)
            orow[col6[ci]] = pacc[mi][ci][r] + bias6[ci];
        }
      }
    }
  }
}

// --------------------------------------------------------------------------
extern "C" void kernel_launch(void* const* d_in, const int* in_sizes, int n_in,
                              void* d_out, int out_size, void* d_ws,
                              size_t ws_size, hipStream_t stream) {
  const float* x     = (const float*)d_in[0];
  const float* wqkv  = (const float*)d_in[1];
  const float* bqkv  = (const float*)d_in[2];
  const float* wproj = (const float*)d_in[3];
  const float* bproj = (const float*)d_in[4];
  const float* table = (const float*)d_in[5];
  float* out = (float*)d_out;

  char* ws = (char*)d_ws;
  bf16* bmb = (bf16*)(ws + BM_OFF);
  bf16* wqg = (bf16*)(ws + WQ_OFF);
  bf16* wpg = (bf16*)(ws + WP_OFF);

  k_prep<<<dim3(12576), dim3(256), 0, stream>>>(wqkv, wproj, table,
                                                wqg, wpg, bmb);
  k_fused<<<dim3(2048), dim3(256), 0, stream>>>(x, wqg, bqkv, bmb,
                                                wpg, bproj, out);
}

// Round 5
// 581.481 us; speedup vs baseline: 1.0178x; 1.0178x over previous
//
#include <hip/hip_runtime.h>

// ---------------------------------------------------------------------------
// Shifted-window attention (Swin), MI355X bf16-MFMA, round 8 (= round-7
// resubmit; prior bench failed on container infra, not the kernel).
// Proven r0 4-kernel pipeline with the xg round-trip eliminated: the
// gather(roll -3,-3)+window-partition+fp32->bf16 is fused into k_qkv's
// A-staging (reg-stage + swizzled ds_write; B stays global_load_lds).
// k_attn / k_proj / epilogues are r0-verbatim.
// ---------------------------------------------------------------------------

typedef __bf16 bf16;
typedef __bf16 bf16x8 __attribute__((ext_vector_type(8)));
typedef __bf16 bf16x4 __attribute__((ext_vector_type(4)));
typedef float f32x4 __attribute__((ext_vector_type(4)));

#define QKV_SCALE 0.17677669529663687f

// workspace offsets (bytes); total 315,752,448 <= 331,874,304 (known safe)
#define QB_OFF 0u
#define KB_OFF 77070336u
#define VB_OFF 154140672u      // v [WHN][49][32]
#define AB_OFF 231211008u      // ab bf16 [GTOK][384]
#define BM_OFF 308281344u      // bias+mask bf16, fragment order [768][4096]
#define WQ_OFF 314572800u      // wqkv bf16 [1152][384]
#define WP_OFF 315457536u      // wproj bf16 [384][384]

__device__ inline void gld16(const bf16* g, bf16* l) {
  __builtin_amdgcn_global_load_lds(
      (const __attribute__((address_space(1))) void*)g,
      (__attribute__((address_space(3))) void*)l, 16, 0, 0);
}

// --------------------------------------------------------------------------
// prep: [0,288) weight cvt   [288,12576) bias+mask table
// --------------------------------------------------------------------------
__global__ __launch_bounds__(256) void k_prep(
    const float* __restrict__ wqkv, const float* __restrict__ wproj,
    const float* __restrict__ table, bf16* __restrict__ wq,
    bf16* __restrict__ wp, bf16* __restrict__ bm) {
  int blk = blockIdx.x;
  if (blk < 288) {
    int idx = blk * 256 + threadIdx.x;            // < 73728
    const float* src; bf16* dst; int off;
    if (idx < 55296) { src = wqkv; dst = wq; off = idx * 8; }
    else             { src = wproj; dst = wp; off = (idx - 55296) * 8; }
    float4 a0 = *(const float4*)(src + off);
    float4 a1 = *(const float4*)(src + off + 4);
    bf16x8 o;
    o[0] = (bf16)a0.x; o[1] = (bf16)a0.y; o[2] = (bf16)a0.z; o[3] = (bf16)a0.w;
    o[4] = (bf16)a1.x; o[5] = (bf16)a1.y; o[6] = (bf16)a1.z; o[7] = (bf16)a1.w;
    *(bf16x8*)(dst + off) = o;
  } else {
    // frag-ordered bias+mask: bm[(wi*12+h)*4096 + (ts*4+c)*256 + lane*4 + r]
    int idx = (blk - 288) * 256 + threadIdx.x;    // < 3,145,728
    int r = idx & 3;
    int lane = (idx >> 2) & 63;
    int c = (idx >> 8) & 3;
    int ts = (idx >> 10) & 3;
    int comb = idx >> 12;                          // < 768
    int h = comb % 12, wi = comb / 12;
    int i = ts * 16 + ((lane >> 4) << 2) + r;
    int j = c * 16 + (lane & 15);
    float v;
    if (j >= 49) v = -30000.f;
    else if (i >= 49) v = 0.f;
    else {
      int wy = wi >> 3, wx = wi & 7;
      int iy = i / 7, ix = i - iy * 7;
      int jy = j / 7, jx = j - jy * 7;
      int rel = (iy - jy + 6) * 13 + (ix - jx + 6);
      int gyi = wy * 7 + iy, gxi = wx * 7 + ix;
      int gyj = wy * 7 + jy, gxj = wx * 7 + jx;
      int ri = ((gyi < 49) ? 0 : ((gyi < 53) ? 1 : 2)) * 3 +
               ((gxi < 49) ? 0 : ((gxi < 53) ? 1 : 2));
      int rj = ((gyj < 49) ? 0 : ((gyj < 53) ? 1 : 2)) * 3 +
               ((gxj < 49) ? 0 : ((gxj < 53) ? 1 : 2));
      v = table[rel * 12 + h] + ((ri == rj) ? 0.f : -100.f);
    }
    bm[idx] = (bf16)v;
  }
}

// --------------------------------------------------------------------------
// QKV GEMM [GTOK x 1152, K=384] with fused input gather.
// 128x128 tile, BK=64. A: reg-stage fp32 x (roll+window index) -> bf16 ->
// XOR-swizzled ds_write. B: global_load_lds w=16 from pre-swizzled source.
// XCD swizzle: xcd=bid&7, n fastest within XCD.
// --------------------------------------------------------------------------
__global__ __launch_bounds__(256, 3) void k_qkv(
    const float* __restrict__ x, const bf16* __restrict__ wg,
    const float* __restrict__ bqkv, bf16* __restrict__ qb,
    bf16* __restrict__ kb, bf16* __restrict__ vb) {
  __shared__ __align__(16) bf16 As[128 * 64];
  __shared__ __align__(16) bf16 Bs[128 * 64];

  int tid = threadIdx.x;
  int wv = tid >> 6, lane = tid & 63, l16 = lane & 15, q4 = lane >> 4;
  int wr = wv >> 1, wc = wv & 1;
  int bid = blockIdx.x;              // 7056
  int xcd = bid & 7, s = bid >> 3;
  int nb = s % 9, mt = s / 9;        // nb fastest within an XCD
  int m0 = (mt * 8 + xcd) * 128;
  int n0 = nb * 128;

  int srow = lane >> 3;
  int scg = lane & 7;

  // A-gather source: this thread's fixed tile row + 32-col half
  int arow = tid >> 1, ahalf = tid & 1;
  int mrow = m0 + arow;                         // < 100352 always
  int wA = mrow / 49, tA = mrow - wA * 49;
  int bA = wA >> 6, wiA = wA & 63;
  int wyA = wiA >> 3, wxA = wiA & 7;
  int tyA = tA / 7, txA = tA - tyA * 7;
  int syA = wyA * 7 + tyA + 3; if (syA >= 56) syA -= 56;
  int sxA = wxA * 7 + txA + 3; if (sxA >= 56) sxA -= 56;
  const float* xrow = x + (size_t)((bA * 56 + syA) * 56 + sxA) * 384 + ahalf * 32;
  bf16* adst = As + arow * 64;
  int ar7 = arow & 7;

  f32x4 acc[4][4];
#pragma unroll
  for (int a = 0; a < 4; ++a)
#pragma unroll
    for (int b = 0; b < 4; ++b) acc[a][b] = (f32x4){0.f, 0.f, 0.f, 0.f};

  for (int k0 = 0; k0 < 384; k0 += 64) {
    // issue A-gather loads before the barrier (overlap with prev MFMA drain)
    float4 f[8];
#pragma unroll
    for (int j = 0; j < 8; ++j) f[j] = *(const float4*)(xrow + k0 + j * 4);
    __syncthreads();
#pragma unroll
    for (int st = 0; st < 4; ++st) {
      int row = (wv * 4 + st) * 8 + srow;
      int gc = (scg ^ (row & 7)) * 8;
      gld16(wg + (size_t)(n0 + row) * 384 + k0 + gc, Bs + (wv * 4 + st) * 512);
    }
#pragma unroll
    for (int j2 = 0; j2 < 4; ++j2) {
      bf16x8 o;
      o[0] = (bf16)f[2 * j2].x;     o[1] = (bf16)f[2 * j2].y;
      o[2] = (bf16)f[2 * j2].z;     o[3] = (bf16)f[2 * j2].w;
      o[4] = (bf16)f[2 * j2 + 1].x; o[5] = (bf16)f[2 * j2 + 1].y;
      o[6] = (bf16)f[2 * j2 + 1].z; o[7] = (bf16)f[2 * j2 + 1].w;
      int g = ahalf * 4 + j2;
      *(bf16x8*)(adst + ((g ^ ar7) << 3)) = o;
    }
    __syncthreads();
#pragma unroll
    for (int kk = 0; kk < 2; ++kk) {
      bf16x8 af[4], bfr[4];
#pragma unroll
      for (int mi = 0; mi < 4; ++mi) {
        int m = wr * 64 + mi * 16 + l16;
        int g = kk * 4 + q4;
        af[mi] = *(const bf16x8*)(As + m * 64 + ((g ^ (m & 7)) * 8));
      }
#pragma unroll
      for (int ci = 0; ci < 4; ++ci) {
        int n = wc * 64 + ci * 16 + l16;
        int g = kk * 4 + q4;
        bfr[ci] = *(const bf16x8*)(Bs + n * 64 + ((g ^ (n & 7)) * 8));
      }
#pragma unroll
      for (int mi = 0; mi < 4; ++mi)
#pragma unroll
        for (int ci = 0; ci < 4; ++ci)
          acc[mi][ci] =
              __builtin_amdgcn_mfma_f32_16x16x32_bf16(af[mi], bfr[ci], acc[mi][ci], 0, 0, 0);
    }
  }

  int which = nb / 3;                // 0:q 1:k 2:v (uniform per block)
  float bias4[4]; int h4[4], d4[4];
#pragma unroll
  for (int ci = 0; ci < 4; ++ci) {
    int n = n0 + wc * 64 + ci * 16 + l16;
    bias4[ci] = bqkv[n];
    int hd = n - which * 384;
    h4[ci] = hd >> 5; d4[ci] = hd & 31;
  }
#pragma unroll
  for (int mi = 0; mi < 4; ++mi) {
#pragma unroll
    for (int r = 0; r < 4; ++r) {
      int mr = m0 + wr * 64 + mi * 16 + q4 * 4 + r;
      int w = mr / 49, tt = mr - w * 49;
      int wb = w * 12;
#pragma unroll
      for (int ci = 0; ci < 4; ++ci) {
        float val = acc[mi][ci][r] + bias4[ci];
        size_t addr = (size_t)((wb + h4[ci]) * 49 + tt) * 32 + d4[ci];
        if (which == 0)
          qb[addr] = (bf16)(val * QKV_SCALE);
        else if (which == 1)
          kb[addr] = (bf16)val;
        else
          vb[addr] = (bf16)val;
      }
    }
  }
}

// --------------------------------------------------------------------------
// Attention: one wave per (window, head), barrier-free. grid 6144 x 256.
// Masked P columns (j>=49) are exactly 0 -> V needs no padding rows.
// --------------------------------------------------------------------------
__global__ __launch_bounds__(256) void k_attn(
    const bf16* __restrict__ qb, const bf16* __restrict__ kb,
    const bf16* __restrict__ vb, const bf16* __restrict__ bm,
    bf16* __restrict__ ab) {
  __shared__ __align__(16) bf16 P[4][16][72];

  int tid = threadIdx.x;
  int wv = tid >> 6, lane = tid & 63, l16 = lane & 15, q4 = lane >> 4;
  int whi = blockIdx.x * 4 + wv;
  int w = whi / 12, h = whi - w * 12;
  int wi = w & 63;

  const bf16* qq = qb + (size_t)whi * 1568;
  const bf16* kk = kb + (size_t)whi * 1568;
  const bf16* vv = vb + (size_t)whi * 1568;
  const bf16* bmb = bm + ((size_t)(wi * 12 + h) << 12);

  // K fragments (rows >=49 are garbage; masked by bm)
  bf16x8 kf[4];
#pragma unroll
  for (int c = 0; c < 4; ++c)
    kf[c] = *(const bf16x8*)(kk + (c * 16 + l16) * 32 + q4 * 8);

  // V B-fragments: vf[half][c2][j] = v[tok = half*32 + q4*8 + j][c2*16+l16]
  bf16x8 vf[2][2];
#pragma unroll
  for (int half = 0; half < 2; ++half)
#pragma unroll
    for (int c2 = 0; c2 < 2; ++c2)
#pragma unroll
      for (int j = 0; j < 8; ++j)
        vf[half][c2][j] = vv[(half * 32 + q4 * 8 + j) * 32 + c2 * 16 + l16];

  const f32x4 zero4 = {0.f, 0.f, 0.f, 0.f};

  for (int ts = 0; ts < 4; ++ts) {
    bf16x8 qf = *(const bf16x8*)(qq + (ts * 16 + l16) * 32 + q4 * 8);
    f32x4 s[4];
#pragma unroll
    for (int c = 0; c < 4; ++c)
      s[c] = __builtin_amdgcn_mfma_f32_16x16x32_bf16(qf, kf[c], zero4, 0, 0, 0);
#pragma unroll
    for (int c = 0; c < 4; ++c) {
      bf16x4 bv = *(const bf16x4*)(bmb + (ts * 4 + c) * 256 + lane * 4);
#pragma unroll
      for (int r = 0; r < 4; ++r) s[c][r] += (float)bv[r];
    }
#pragma unroll
    for (int r = 0; r < 4; ++r) {
      float m = fmaxf(fmaxf(s[0][r], s[1][r]), fmaxf(s[2][r], s[3][r]));
      m = fmaxf(m, __shfl_xor(m, 1));
      m = fmaxf(m, __shfl_xor(m, 2));
      m = fmaxf(m, __shfl_xor(m, 4));
      m = fmaxf(m, __shfl_xor(m, 8));
      float e0 = __expf(s[0][r] - m);
      float e1 = __expf(s[1][r] - m);
      float e2 = __expf(s[2][r] - m);
      float e3 = __expf(s[3][r] - m);
      float sm = e0 + e1 + e2 + e3;
      sm += __shfl_xor(sm, 1);
      sm += __shfl_xor(sm, 2);
      sm += __shfl_xor(sm, 4);
      sm += __shfl_xor(sm, 8);
      float inv = 1.0f / sm;
      int ir = q4 * 4 + r;
      P[wv][ir][l16] = (bf16)(e0 * inv);
      P[wv][ir][16 + l16] = (bf16)(e1 * inv);
      P[wv][ir][32 + l16] = (bf16)(e2 * inv);
      P[wv][ir][48 + l16] = (bf16)(e3 * inv);
    }
    __builtin_amdgcn_wave_barrier();   // pin ds_write < ds_read order
    bf16x8 p0 = *(const bf16x8*)&P[wv][l16][q4 * 8];
    bf16x8 p1 = *(const bf16x8*)&P[wv][l16][32 + q4 * 8];
    f32x4 o0 = __builtin_amdgcn_mfma_f32_16x16x32_bf16(p0, vf[0][0], zero4, 0, 0, 0);
    o0 = __builtin_amdgcn_mfma_f32_16x16x32_bf16(p1, vf[1][0], o0, 0, 0, 0);
    f32x4 o1 = __builtin_amdgcn_mfma_f32_16x16x32_bf16(p0, vf[0][1], zero4, 0, 0, 0);
    o1 = __builtin_amdgcn_mfma_f32_16x16x32_bf16(p1, vf[1][1], o1, 0, 0, 0);
    __builtin_amdgcn_wave_barrier();   // pin ds_read < next strip's ds_write
#pragma unroll
    for (int r = 0; r < 4; ++r) {
      int i = ts * 16 + q4 * 4 + r;
      if (i < 49) {
        bf16* dst = ab + (size_t)(w * 49 + i) * 384 + h * 32;
        dst[l16] = (bf16)o0[r];
        dst[16 + l16] = (bf16)o1[r];
      }
    }
  }
}

// --------------------------------------------------------------------------
// Proj GEMM [GTOK x 384, K=384] + pixel scatter (roll +3) to fp32 out.
// XCD swizzle, grid 2352.
// --------------------------------------------------------------------------
__global__ __launch_bounds__(256, 3) void k_proj(
    const bf16* __restrict__ ab, const bf16* __restrict__ wp,
    const float* __restrict__ bp, float* __restrict__ out) {
  __shared__ __align__(16) bf16 As[128 * 64];
  __shared__ __align__(16) bf16 Bs[128 * 64];

  int tid = threadIdx.x;
  int wv = tid >> 6, lane = tid & 63, l16 = lane & 15, q4 = lane >> 4;
  int wr = wv >> 1, wc = wv & 1;
  int bid = blockIdx.x;              // 2352
  int xcd = bid & 7, s = bid >> 3;
  int nb = s % 3, mt = s / 3;
  int m0 = (mt * 8 + xcd) * 128;
  int n0 = nb * 128;

  int srow = lane >> 3;
  int scg = lane & 7;

  f32x4 acc[4][4];
#pragma unroll
  for (int a = 0; a < 4; ++a)
#pragma unroll
    for (int b = 0; b < 4; ++b) acc[a][b] = (f32x4){0.f, 0.f, 0.f, 0.f};

  for (int k0 = 0; k0 < 384; k0 += 64) {
    __syncthreads();
#pragma unroll
    for (int st = 0; st < 4; ++st) {
      int row = (wv * 4 + st) * 8 + srow;
      int gc = (scg ^ (row & 7)) * 8;
      gld16(ab + (size_t)(m0 + row) * 384 + k0 + gc, As + (wv * 4 + st) * 512);
      gld16(wp + (size_t)(n0 + row) * 384 + k0 + gc, Bs + (wv * 4 + st) * 512);
    }
    __syncthreads();
#pragma unroll
    for (int kk = 0; kk < 2; ++kk) {
      bf16x8 af[4], bfr[4];
#pragma unroll
      for (int mi = 0; mi < 4; ++mi) {
        int m = wr * 64 + mi * 16 + l16;
        int g = kk * 4 + q4;
        af[mi] = *(const bf16x8*)(As + m * 64 + ((g ^ (m & 7)) * 8));
      }
#pragma unroll
      for (int ci = 0; ci < 4; ++ci) {
        int n = wc * 64 + ci * 16 + l16;
        int g = kk * 4 + q4;
        bfr[ci] = *(const bf16x8*)(Bs + n * 64 + ((g ^ (n & 7)) * 8));
      }
#pragma unroll
      for (int mi = 0; mi < 4; ++mi)
#pragma unroll
        for (int ci = 0; ci < 4; ++ci)
          acc[mi][ci] =
              __builtin_amdgcn_mfma_f32_16x16x32_bf16(af[mi], bfr[ci], acc[mi][ci], 0, 0, 0);
    }
  }

  float bias4[4]; int col4[4];
#pragma unroll
  for (int ci = 0; ci < 4; ++ci) {
    col4[ci] = n0 + wc * 64 + ci * 16 + l16;
    bias4[ci] = bp[col4[ci]];
  }
#pragma unroll
  for (int mi = 0; mi < 4; ++mi) {
#pragma unroll
    for (int r = 0; r < 4; ++r) {
      int mr = m0 + wr * 64 + mi * 16 + q4 * 4 + r;
      int w = mr / 49, t = mr - w * 49;
      int b = w >> 6, wi = w & 63;
      int wy = wi >> 3, wx = wi & 7;
      int ty = t / 7, tx = t - ty * 7;
      int gy = wy * 7 + ty + 3; if (gy >= 56) gy -= 56;
      int gx = wx * 7 + tx + 3; if (gx >= 56) gx -= 56;
      float* orow = out + (size_t)((b * 56 + gy) * 56 + gx) * 384;
#pragma unroll
      for (int ci = 0; ci < 4; ++ci) orow[col4[ci]] = acc[mi][ci][r] + bias4[ci];
    }
  }
}

// --------------------------------------------------------------------------
extern "C" void kernel_launch(void* const* d_in, const int* in_sizes, int n_in,
                              void* d_out, int out_size, void* d_ws,
                              size_t ws_size, hipStream_t stream) {
  const float* x     = (const float*)d_in[0];
  const float* wqkv  = (const float*)d_in[1];
  const float* bqkv  = (const float*)d_in[2];
  const float* wproj = (const float*)d_in[3];
  const float* bproj = (const float*)d_in[4];
  const float* table = (const float*)d_in[5];
  float* out = (float*)d_out;

  char* ws = (char*)d_ws;
  bf16* qb  = (bf16*)(ws + QB_OFF);
  bf16* kb  = (bf16*)(ws + KB_OFF);
  bf16* vb  = (bf16*)(ws + VB_OFF);
  bf16* ab  = (bf16*)(ws + AB_OFF);
  bf16* bmb = (bf16*)(ws + BM_OFF);
  bf16* wqg = (bf16*)(ws + WQ_OFF);
  bf16* wpg = (bf16*)(ws + WP_OFF);

  k_prep<<<dim3(12576), dim3(256), 0, stream>>>(wqkv, wproj, table,
                                                wqg, wpg, bmb);
  k_qkv<<<dim3(7056), dim3(256), 0, stream>>>(x, wqg, bqkv, qb, kb, vb);
  k_attn<<<dim3(6144), dim3(256), 0, stream>>>(qb, kb, vb, bmb, ab);
  k_proj<<<dim3(2352), dim3(256), 0, stream>>>(ab, wpg, bproj, out);
}